// Round 2
// baseline (310.337 us; speedup 1.0000x reference)
//
#include <hip/hip_runtime.h>
#include <hip/hip_bf16.h>
#include <stdint.h>

#define BATCH 8192
#define INF   1024
#define GN    1024
#define GK    8192   // 8 degrees (d=1..8) * 1024; d=0 handled as f32 bias

typedef __attribute__((ext_vector_type(4))) float floatx4;
typedef __attribute__((ext_vector_type(8))) short short8;

static __device__ __forceinline__ ushort f2bf(float f) {
  union { float f; uint32_t u; } v; v.f = f;
  uint32_t r = v.u + 0x7FFF + ((v.u >> 16) & 1);   // RNE
  return (ushort)(r >> 16);
}

// ---------------------------------------------------------------------------
// bias[o] = sum_i coef[i,o,0]   (f32, keeps the T0=1 plane exact)
// grid 32 (i-chunks of 32), block 1024 (one thread per o)
__global__ void bias_kernel(const float* __restrict__ coef, float* __restrict__ bias) {
  const int o = threadIdx.x;
  const int i0 = blockIdx.x << 5;
  float s = 0.f;
  #pragma unroll
  for (int ii = 0; ii < 32; ++ii)
    s += coef[(size_t)(i0 + ii) * 9216 + (size_t)o * 9];
  atomicAdd(&bias[o], s);
}

// ---------------------------------------------------------------------------
// Repack coef (I,O,9) f32 -> Wt bf16 [O][K] with k = (d-1)*1024 + i, d=1..8.
// LDS transpose per 32x32 (i,o) tile: coalesced reads AND coalesced writes.
__global__ __launch_bounds__(256) void repack(const float* __restrict__ coef,
                                              ushort* __restrict__ Wt) {
  __shared__ ushort lds[32 * 9 * 33];        // [oo*9+d][ii], pad 33 vs banks
  const int i0 = (blockIdx.x >> 5) << 5;
  const int o0 = (blockIdx.x & 31) << 5;
  const int t = threadIdx.x;
  for (int idx = t; idx < 32 * 288; idx += 256) {
    const int ii  = idx / 288;
    const int rem = idx - ii * 288;          // oo*9 + d
    const float f = coef[(size_t)(i0 + ii) * 9216 + (size_t)o0 * 9 + rem];
    lds[rem * 33 + ii] = f2bf(f);
  }
  __syncthreads();
  for (int idx = t; idx < 32 * 8 * 32; idx += 256) {
    const int oo  = idx >> 8;
    const int rem = idx & 255;
    const int d1  = rem >> 5;                // 0..7  -> degree d1+1
    const int ii  = rem & 31;
    Wt[(size_t)(o0 + oo) * GK + (size_t)d1 * 1024 + (i0 + ii)] =
        lds[(oo * 9 + d1 + 1) * 33 + ii];
  }
}

// ---------------------------------------------------------------------------
// Featurize: Cf[b][ (d-1)*1024 + i ] = bf16(T_d(tanh(x[b,i]))), d=1..8.
// One thread per 4 elements; f32 recursion, bf16 store.
__global__ __launch_bounds__(256) void featurize(const float* __restrict__ x,
                                                 ushort* __restrict__ Cf) {
  const int tid = blockIdx.x * 256 + threadIdx.x;
  const size_t idx4 = (size_t)tid << 2;
  const int b = tid >> 8;                    // idx4 / 1024
  const int i = (tid & 255) << 2;
  const float4 v = *reinterpret_cast<const float4*>(x + idx4);
  float t[4] = {tanhf(v.x), tanhf(v.y), tanhf(v.z), tanhf(v.w)};
  float Tp[4] = {1.f, 1.f, 1.f, 1.f};        // T_{d-1}
  float Tc[4] = {t[0], t[1], t[2], t[3]};    // T_d, starting d=1
  ushort* base = Cf + (size_t)b * GK + i;
  #pragma unroll
  for (int d = 1; d <= 8; ++d) {
    ushort4 u;
    u.x = f2bf(Tc[0]); u.y = f2bf(Tc[1]); u.z = f2bf(Tc[2]); u.w = f2bf(Tc[3]);
    *reinterpret_cast<ushort4*>(base + (size_t)(d - 1) * 1024) = u;
    #pragma unroll
    for (int j = 0; j < 4; ++j) {
      const float Tn = 2.f * t[j] * Tc[j] - Tp[j];
      Tp[j] = Tc[j]; Tc[j] = Tn;
    }
  }
}

// ---------------------------------------------------------------------------
// bf16 GEMM, m97 structure: 128x128 tile, BK=32, 4 waves (2x2), each wave a
// 64x64 subtile = 4x4 frags of 16x16x32. global_load_lds width-16 staging.
__global__ __launch_bounds__(256) void gemm_bt(const ushort* __restrict__ A,   // [BATCH][GK]
                                               const ushort* __restrict__ Bt,  // [GN][GK]
                                               const float* __restrict__ bias, // [GN]
                                               float* __restrict__ C) {        // [BATCH][GN]
  __shared__ __align__(16) ushort As[128 * 32];
  __shared__ __align__(16) ushort Bs[128 * 32];
  const int t = threadIdx.x;
  // bijective XCD swizzle: 512 blocks -> 64 contiguous per XCD
  const int bid = (blockIdx.x & 7) * 64 + (blockIdx.x >> 3);
  const int bm0 = (bid >> 3) << 7;
  const int bn0 = (bid & 7) << 7;
  const int lane = t & 63;
  const int wid = t >> 6;
  const int wm0 = (wid >> 1) << 6;
  const int wn0 = (wid & 1) << 6;
  const int lr = lane & 15;
  const int lk = lane >> 4;

  const int srow  = t >> 2;                  // staging row (0..63)
  const int scolb = (t & 3) << 4;            // staging byte-in-row

  const char* gA0 = (const char*)(A  + (size_t)(bm0 + srow) * GK) + scolb;
  const char* gB0 = (const char*)(Bt + (size_t)(bn0 + srow) * GK) + scolb;
  const size_t rstride = (size_t)64 * GK * 2;   // +64 rows, bytes

  floatx4 acc[4][4] = {};

  for (int k0 = 0; k0 < GK; k0 += 32) {
    const size_t kb = (size_t)k0 * 2;
    __builtin_amdgcn_global_load_lds(
        (const __attribute__((address_space(1))) void*)(gA0 + kb),
        (__attribute__((address_space(3))) void*)((char*)As + t * 16), 16, 0, 0);
    __builtin_amdgcn_global_load_lds(
        (const __attribute__((address_space(1))) void*)(gA0 + kb + rstride),
        (__attribute__((address_space(3))) void*)((char*)As + 4096 + t * 16), 16, 0, 0);
    __builtin_amdgcn_global_load_lds(
        (const __attribute__((address_space(1))) void*)(gB0 + kb),
        (__attribute__((address_space(3))) void*)((char*)Bs + t * 16), 16, 0, 0);
    __builtin_amdgcn_global_load_lds(
        (const __attribute__((address_space(1))) void*)(gB0 + kb + rstride),
        (__attribute__((address_space(3))) void*)((char*)Bs + 4096 + t * 16), 16, 0, 0);
    __syncthreads();

    short8 af[4], bf[4];
    #pragma unroll
    for (int mi = 0; mi < 4; ++mi)
      af[mi] = *reinterpret_cast<const short8*>(&As[(wm0 + mi * 16 + lr) * 32 + lk * 8]);
    #pragma unroll
    for (int ni = 0; ni < 4; ++ni)
      bf[ni] = *reinterpret_cast<const short8*>(&Bs[(wn0 + ni * 16 + lr) * 32 + lk * 8]);
    #pragma unroll
    for (int mi = 0; mi < 4; ++mi)
      #pragma unroll
      for (int ni = 0; ni < 4; ++ni)
        acc[mi][ni] = __builtin_amdgcn_mfma_f32_16x16x32_bf16(af[mi], bf[ni], acc[mi][ni], 0, 0, 0);
    __syncthreads();
  }

  // epilogue: C[row][col] = acc + bias[col]; D layout: col=lane&15, row=lk*4+r
  #pragma unroll
  for (int ni = 0; ni < 4; ++ni) {
    const int col = bn0 + wn0 + ni * 16 + lr;
    const float bv = bias[col];
    #pragma unroll
    for (int mi = 0; mi < 4; ++mi) {
      const int row = bm0 + wm0 + mi * 16 + lk * 4;
      #pragma unroll
      for (int r = 0; r < 4; ++r)
        C[(size_t)(row + r) * GN + col] = acc[mi][ni][r] + bv;
    }
  }
}

// ---------------------------------------------------------------------------
extern "C" void kernel_launch(void* const* d_in, const int* in_sizes, int n_in,
                              void* d_out, int out_size, void* d_ws, size_t ws_size,
                              hipStream_t stream) {
  const float* x    = (const float*)d_in[0];
  const float* coef = (const float*)d_in[1];
  float* out = (float*)d_out;

  char* ws = (char*)d_ws;
  ushort* Cf   = (ushort*)ws;                                   // 8192*8192*2 = 128 MiB
  ushort* Wt   = (ushort*)(ws + (size_t)BATCH * GK * 2);        // 1024*8192*2 =  16 MiB
  float*  bias = (float*)(ws + (size_t)BATCH * GK * 2 + (size_t)GN * GK * 2);

  hipMemsetAsync(bias, 0, GN * sizeof(float), stream);
  bias_kernel<<<32, 1024, 0, stream>>>(coef, bias);
  repack<<<1024, 256, 0, stream>>>(coef, Wt);
  featurize<<<(BATCH * INF / 4) / 256, 256, 0, stream>>>(x, Cf);
  gemm_bt<<<512, 256, 0, stream>>>(Cf, Wt, bias, out);
}

// Round 3
// 274.653 us; speedup vs baseline: 1.1299x; 1.1299x over previous
//
#include <hip/hip_runtime.h>
#include <hip/hip_bf16.h>
#include <stdint.h>

#define BATCH 8192
#define INF   1024
#define GN    1024
#define GK    8192   // 8 degrees (d=1..8) * 1024; d=0 handled as f32 bias

typedef __attribute__((ext_vector_type(4))) float floatx4;
typedef __attribute__((ext_vector_type(8))) short short8;

static __device__ __forceinline__ ushort f2bf(float f) {
  union { float f; uint32_t u; } v; v.f = f;
  uint32_t r = v.u + 0x7FFF + ((v.u >> 16) & 1);   // RNE
  return (ushort)(r >> 16);
}

// ---------------------------------------------------------------------------
// Repack coef (I,O,9) f32 -> Wt bf16 [O][K] with k = (d-1)*1024 + i, d=1..8.
// Also folds the d=0 plane reduction (bias[o] = sum_i coef[i,o,0]) in f32:
// removes the old bias_kernel and its ~37 MiB stride-9 refetch.
__global__ __launch_bounds__(256) void repack(const float* __restrict__ coef,
                                              ushort* __restrict__ Wt,
                                              float* __restrict__ bias) {
  __shared__ ushort lds[32 * 9 * 33];        // [oo*9+d][ii], pad 33 vs banks
  __shared__ float  bl[32 * 33];             // [oo][ii] f32 d=0 plane
  const int i0 = (blockIdx.x >> 5) << 5;
  const int o0 = (blockIdx.x & 31) << 5;
  const int t = threadIdx.x;
  for (int idx = t; idx < 32 * 288; idx += 256) {
    const int ii  = idx / 288;
    const int rem = idx - ii * 288;          // oo*9 + d
    const float f = coef[(size_t)(i0 + ii) * 9216 + (size_t)o0 * 9 + rem];
    lds[rem * 33 + ii] = f2bf(f);
    const int oo = rem / 9;
    if (rem == oo * 9) bl[oo * 33 + ii] = f; // d==0 plane, exact f32
  }
  __syncthreads();
  if (t < 32) {                              // one lane per oo: f32 row-sum
    float s = 0.f;
    #pragma unroll
    for (int ii = 0; ii < 32; ++ii) s += bl[t * 33 + ii];
    atomicAdd(&bias[o0 + t], s);
  }
  for (int idx = t; idx < 32 * 8 * 32; idx += 256) {
    const int oo  = idx >> 8;
    const int rem = idx & 255;
    const int d1  = rem >> 5;                // 0..7  -> degree d1+1
    const int ii  = rem & 31;
    Wt[(size_t)(o0 + oo) * GK + (size_t)d1 * 1024 + (i0 + ii)] =
        lds[(oo * 9 + d1 + 1) * 33 + ii];
  }
}

// ---------------------------------------------------------------------------
// Featurize: Cf[b][ (d-1)*1024 + i ] = bf16(T_d(tanh(x[b,i]))), d=1..8.
__global__ __launch_bounds__(256) void featurize(const float* __restrict__ x,
                                                 ushort* __restrict__ Cf) {
  const int tid = blockIdx.x * 256 + threadIdx.x;
  const size_t idx4 = (size_t)tid << 2;
  const int b = tid >> 8;
  const int i = (tid & 255) << 2;
  const float4 v = *reinterpret_cast<const float4*>(x + idx4);
  float t[4] = {tanhf(v.x), tanhf(v.y), tanhf(v.z), tanhf(v.w)};
  float Tp[4] = {1.f, 1.f, 1.f, 1.f};
  float Tc[4] = {t[0], t[1], t[2], t[3]};
  ushort* base = Cf + (size_t)b * GK + i;
  #pragma unroll
  for (int d = 1; d <= 8; ++d) {
    ushort4 u;
    u.x = f2bf(Tc[0]); u.y = f2bf(Tc[1]); u.z = f2bf(Tc[2]); u.w = f2bf(Tc[3]);
    *reinterpret_cast<ushort4*>(base + (size_t)(d - 1) * 1024) = u;
    #pragma unroll
    for (int j = 0; j < 4; ++j) {
      const float Tn = 2.f * t[j] * Tc[j] - Tp[j];
      Tp[j] = Tc[j]; Tc[j] = Tn;
    }
  }
}

// ---------------------------------------------------------------------------
// bf16 GEMM: 128x128 tile, BK=64, double-buffered LDS, ONE full-drain barrier
// per K-tile (STAGE(next) -> ds_read(cur)+MFMA -> __syncthreads). XOR-swizzled
// LDS chunks (c ^= row&7) via pre-swizzled global source (linear gload_lds
// dest) to keep ds_read_b128 at 2-way-or-free bank aliasing.
__global__ __launch_bounds__(256) void gemm_bt(const ushort* __restrict__ A,   // [BATCH][GK]
                                               const ushort* __restrict__ Bt,  // [GN][GK]
                                               const float* __restrict__ bias, // [GN]
                                               float* __restrict__ C) {        // [BATCH][GN]
  __shared__ __align__(16) ushort As[2][128 * 64];
  __shared__ __align__(16) ushort Bs[2][128 * 64];
  const int t = threadIdx.x;
  // bijective XCD swizzle: 512 blocks -> 64 contiguous per XCD
  const int bid = (blockIdx.x & 7) * 64 + (blockIdx.x >> 3);
  const int bm0 = (bid >> 3) << 7;
  const int bn0 = (bid & 7) << 7;
  const int lane = t & 63;
  const int wid = t >> 6;
  const int wm0 = (wid >> 1) << 6;
  const int wn0 = (wid & 1) << 6;
  const int lr = lane & 15;
  const int lk = lane >> 4;

  // staging: thread t covers row srow + j*32; source 16B chunk pre-swizzled
  const int srow = t >> 3;                         // 0..31
  const int scol = (((t & 7) ^ (srow & 7)) << 4);  // byte offset in 128B row
  const char* gA0 = (const char*)(A  + (size_t)(bm0 + srow) * GK) + scol;
  const char* gB0 = (const char*)(Bt + (size_t)(bn0 + srow) * GK) + scol;
  const size_t rstride = (size_t)32 * GK * 2;      // +32 rows, bytes

  // read-side swizzled chunk byte-offsets (dest[r][c^(r&7)] == src[r][c])
  const int rc0 = ((0 + lk) ^ (lr & 7)) << 4;      // kk=0 chunk
  const int rc1 = ((4 + lk) ^ (lr & 7)) << 4;      // kk=1 chunk

  floatx4 acc[4][4] = {};

#define STAGE(bufi, k0)                                                        \
  do {                                                                         \
    const size_t kb = (size_t)(k0) * 2;                                        \
    _Pragma("unroll")                                                          \
    for (int j = 0; j < 4; ++j) {                                              \
      __builtin_amdgcn_global_load_lds(                                        \
          (const __attribute__((address_space(1))) void*)(gA0 + kb + j * rstride), \
          (__attribute__((address_space(3))) void*)((char*)As[bufi] + j * 4096 + t * 16), \
          16, 0, 0);                                                           \
      __builtin_amdgcn_global_load_lds(                                        \
          (const __attribute__((address_space(1))) void*)(gB0 + kb + j * rstride), \
          (__attribute__((address_space(3))) void*)((char*)Bs[bufi] + j * 4096 + t * 16), \
          16, 0, 0);                                                           \
    }                                                                          \
  } while (0)

  STAGE(0, 0);
  __syncthreads();

  int cur = 0;
  for (int kt = 0; kt < GK / 64; ++kt) {
    if (kt < GK / 64 - 1) {
      if (cur) STAGE(0, (kt + 1) * 64); else STAGE(1, (kt + 1) * 64);
    }
    const char* Ab = (const char*)As[cur];
    const char* Bb = (const char*)Bs[cur];
    short8 af[4][2], bf[4][2];
    #pragma unroll
    for (int mi = 0; mi < 4; ++mi) {
      const int rb = (wm0 + mi * 16 + lr) * 128;   // row byte base
      af[mi][0] = *reinterpret_cast<const short8*>(Ab + rb + rc0);
      af[mi][1] = *reinterpret_cast<const short8*>(Ab + rb + rc1);
    }
    #pragma unroll
    for (int ni = 0; ni < 4; ++ni) {
      const int rb = (wn0 + ni * 16 + lr) * 128;
      bf[ni][0] = *reinterpret_cast<const short8*>(Bb + rb + rc0);
      bf[ni][1] = *reinterpret_cast<const short8*>(Bb + rb + rc1);
    }
    #pragma unroll
    for (int kk = 0; kk < 2; ++kk)
      #pragma unroll
      for (int mi = 0; mi < 4; ++mi)
        #pragma unroll
        for (int ni = 0; ni < 4; ++ni)
          acc[mi][ni] = __builtin_amdgcn_mfma_f32_16x16x32_bf16(af[mi][kk], bf[ni][kk], acc[mi][ni], 0, 0, 0);
    __syncthreads();   // drains vmcnt (staged next tile) + lgkm, then barrier
    cur ^= 1;
  }
#undef STAGE

  // epilogue: C[row][col] = acc + bias[col]; D layout: col=lane&15, row=lk*4+r
  #pragma unroll
  for (int ni = 0; ni < 4; ++ni) {
    const int col = bn0 + wn0 + ni * 16 + lr;
    const float bv = bias[col];
    #pragma unroll
    for (int mi = 0; mi < 4; ++mi) {
      const int row = bm0 + wm0 + mi * 16 + lk * 4;
      #pragma unroll
      for (int r = 0; r < 4; ++r)
        C[(size_t)(row + r) * GN + col] = acc[mi][ni][r] + bv;
    }
  }
}

// ---------------------------------------------------------------------------
extern "C" void kernel_launch(void* const* d_in, const int* in_sizes, int n_in,
                              void* d_out, int out_size, void* d_ws, size_t ws_size,
                              hipStream_t stream) {
  const float* x    = (const float*)d_in[0];
  const float* coef = (const float*)d_in[1];
  float* out = (float*)d_out;

  char* ws = (char*)d_ws;
  ushort* Cf   = (ushort*)ws;                                   // 128 MiB
  ushort* Wt   = (ushort*)(ws + (size_t)BATCH * GK * 2);        //  16 MiB
  float*  bias = (float*)(ws + (size_t)BATCH * GK * 2 + (size_t)GN * GK * 2);

  hipMemsetAsync(bias, 0, GN * sizeof(float), stream);
  repack<<<1024, 256, 0, stream>>>(coef, Wt, bias);
  featurize<<<(BATCH * INF / 4) / 256, 256, 0, stream>>>(x, Cf);
  gemm_bt<<<512, 256, 0, stream>>>(Cf, Wt, bias, out);
}

// Round 4
// 248.734 us; speedup vs baseline: 1.2477x; 1.1042x over previous
//
#include <hip/hip_runtime.h>
#include <hip/hip_bf16.h>
#include <stdint.h>

#define BATCH 8192
#define INF   1024
#define GN    1024
#define GK    8192   // 8 degrees (d=1..8) * 1024; d=0 handled as f32 bias

#define BM 256
#define BN 128
#define BK 64
#define NT (GK / BK)         // 128 K-tiles
#define ABYTES (BM * BK * 2) // 32768
#define BBYTES (BN * BK * 2) // 16384
#define BUFSZ  (ABYTES + BBYTES)      // 49152
#define SMEM_BYTES (3 * BUFSZ)        // 147456 = 144 KiB (3-deep K-tile pipeline)

typedef __attribute__((ext_vector_type(4))) float floatx4;
typedef __attribute__((ext_vector_type(8))) short short8;

static __device__ __forceinline__ ushort f2bf(float f) {
  union { float f; uint32_t u; } v; v.f = f;
  uint32_t r = v.u + 0x7FFF + ((v.u >> 16) & 1);   // RNE
  return (ushort)(r >> 16);
}

// ---------------------------------------------------------------------------
// Repack coef (I,O,9) f32 -> Wt bf16 [O][K], k=(d-1)*1024+i; fold d=0 bias.
__global__ __launch_bounds__(256) void repack(const float* __restrict__ coef,
                                              ushort* __restrict__ Wt,
                                              float* __restrict__ bias) {
  __shared__ ushort lds[32 * 9 * 33];
  __shared__ float  bl[32 * 33];
  const int i0 = (blockIdx.x >> 5) << 5;
  const int o0 = (blockIdx.x & 31) << 5;
  const int t = threadIdx.x;
  for (int idx = t; idx < 32 * 288; idx += 256) {
    const int ii  = idx / 288;
    const int rem = idx - ii * 288;          // oo*9 + d
    const float f = coef[(size_t)(i0 + ii) * 9216 + (size_t)o0 * 9 + rem];
    lds[rem * 33 + ii] = f2bf(f);
    const int oo = rem / 9;
    if (rem == oo * 9) bl[oo * 33 + ii] = f;
  }
  __syncthreads();
  if (t < 32) {
    float s = 0.f;
    #pragma unroll
    for (int ii = 0; ii < 32; ++ii) s += bl[t * 33 + ii];
    atomicAdd(&bias[o0 + t], s);
  }
  for (int idx = t; idx < 32 * 8 * 32; idx += 256) {
    const int oo  = idx >> 8;
    const int rem = idx & 255;
    const int d1  = rem >> 5;
    const int ii  = rem & 31;
    Wt[(size_t)(o0 + oo) * GK + (size_t)d1 * 1024 + (i0 + ii)] =
        lds[(oo * 9 + d1 + 1) * 33 + ii];
  }
}

// ---------------------------------------------------------------------------
__global__ __launch_bounds__(256) void featurize(const float* __restrict__ x,
                                                 ushort* __restrict__ Cf) {
  const int tid = blockIdx.x * 256 + threadIdx.x;
  const size_t idx4 = (size_t)tid << 2;
  const int b = tid >> 8;
  const int i = (tid & 255) << 2;
  const float4 v = *reinterpret_cast<const float4*>(x + idx4);
  float t[4] = {tanhf(v.x), tanhf(v.y), tanhf(v.z), tanhf(v.w)};
  float Tp[4] = {1.f, 1.f, 1.f, 1.f};
  float Tc[4] = {t[0], t[1], t[2], t[3]};
  ushort* base = Cf + (size_t)b * GK + i;
  #pragma unroll
  for (int d = 1; d <= 8; ++d) {
    ushort4 u;
    u.x = f2bf(Tc[0]); u.y = f2bf(Tc[1]); u.z = f2bf(Tc[2]); u.w = f2bf(Tc[3]);
    *reinterpret_cast<ushort4*>(base + (size_t)(d - 1) * 1024) = u;
    #pragma unroll
    for (int j = 0; j < 4; ++j) {
      const float Tn = 2.f * t[j] * Tc[j] - Tp[j];
      Tp[j] = Tc[j]; Tc[j] = Tn;
    }
  }
}

// ---------------------------------------------------------------------------
// bf16 GEMM, 4-phase counted-vmcnt schedule (T3+T4+T5), BM=256 BN=128 BK=64,
// 512 threads (8 waves, 4M x 2N, 64x64 each), triple-buffered LDS (144 KiB).
// Ledger: tile t computes buf[t%3]; stages tile t+2 into buf[(t+2)%3] (last
// read at tile t-1 -> race-free). vmcnt(6) at p3 = next-next tile's 6 issues
// outstanding -> drains next tile's loads. Barrier after vmcnt certifies LDS.

__device__ __forceinline__ void gload16(const char* src, char* dstp) {
  __builtin_amdgcn_global_load_lds(
      (const __attribute__((address_space(1))) void*)src,
      (__attribute__((address_space(3))) void*)dstp, 16, 0, 0);
}

template<int CB, int NB, bool DOSTAGE, bool VM6>
__device__ __forceinline__ void tile_step(char* smem, int kt,
    const char* const* gA, const char* const* gB, int dst,
    int wm0, int wn0, int lr, int lk, floatx4 (&acc)[4][4]) {
  const char* Ab = smem + CB * BUFSZ;
  const char* Bb = smem + CB * BUFSZ + ABYTES;
  const int xm = lr & 7;
  const size_t kb = (size_t)(kt + 2) * 128;    // staged tile's k byte offset
  short8 af[4][2], bf[4][2];

#define QUAD(MI0, NI0)                                                         \
  __builtin_amdgcn_s_setprio(1);                                               \
  _Pragma("unroll") for (int kk = 0; kk < 2; ++kk)                             \
    _Pragma("unroll") for (int mi = MI0; mi < MI0 + 2; ++mi)                   \
      _Pragma("unroll") for (int ni = NI0; ni < NI0 + 2; ++ni)                 \
        acc[mi][ni] = __builtin_amdgcn_mfma_f32_16x16x32_bf16(                 \
            af[mi][kk], bf[ni][kk], acc[mi][ni], 0, 0, 0);                     \
  __builtin_amdgcn_s_setprio(0);

  // ---- phase 0: read af[0..1], bf[0..1]; stage A-slabs 0,1; MFMA q(0,0)
  #pragma unroll
  for (int mi = 0; mi < 2; ++mi)
    #pragma unroll
    for (int kk = 0; kk < 2; ++kk)
      af[mi][kk] = *reinterpret_cast<const short8*>(
          Ab + (wm0 + mi * 16 + lr) * 128 + ((((kk << 2) | lk) ^ xm) << 4));
  #pragma unroll
  for (int ni = 0; ni < 2; ++ni)
    #pragma unroll
    for (int kk = 0; kk < 2; ++kk)
      bf[ni][kk] = *reinterpret_cast<const short8*>(
          Bb + (wn0 + ni * 16 + lr) * 128 + ((((kk << 2) | lk) ^ xm) << 4));
  if (DOSTAGE) {
    gload16(gA[0] + kb, smem + NB * BUFSZ + 0 * 8192 + dst);
    gload16(gA[1] + kb, smem + NB * BUFSZ + 1 * 8192 + dst);
  }
  __builtin_amdgcn_s_barrier();
  __builtin_amdgcn_sched_barrier(0);
  QUAD(0, 0)

  // ---- phase 1: read af[2..3], bf[2..3]; stage A-slabs 2,3; MFMA q(0,1)
  #pragma unroll
  for (int mi = 2; mi < 4; ++mi)
    #pragma unroll
    for (int kk = 0; kk < 2; ++kk)
      af[mi][kk] = *reinterpret_cast<const short8*>(
          Ab + (wm0 + mi * 16 + lr) * 128 + ((((kk << 2) | lk) ^ xm) << 4));
  #pragma unroll
  for (int ni = 2; ni < 4; ++ni)
    #pragma unroll
    for (int kk = 0; kk < 2; ++kk)
      bf[ni][kk] = *reinterpret_cast<const short8*>(
          Bb + (wn0 + ni * 16 + lr) * 128 + ((((kk << 2) | lk) ^ xm) << 4));
  if (DOSTAGE) {
    gload16(gA[2] + kb, smem + NB * BUFSZ + 2 * 8192 + dst);
    gload16(gA[3] + kb, smem + NB * BUFSZ + 3 * 8192 + dst);
  }
  __builtin_amdgcn_s_barrier();
  __builtin_amdgcn_sched_barrier(0);
  QUAD(0, 2)

  // ---- phase 2: stage B-slabs 0,1; MFMA q(1,0)
  if (DOSTAGE) {
    gload16(gB[0] + kb, smem + NB * BUFSZ + ABYTES + 0 * 8192 + dst);
    gload16(gB[1] + kb, smem + NB * BUFSZ + ABYTES + 1 * 8192 + dst);
  }
  __builtin_amdgcn_s_barrier();
  __builtin_amdgcn_sched_barrier(0);
  QUAD(2, 0)

  // ---- phase 3: counted vmcnt (drain next tile's 6 loads), certify, q(1,1)
  if (VM6) asm volatile("s_waitcnt vmcnt(6)" ::: "memory");
  else     asm volatile("s_waitcnt vmcnt(0)" ::: "memory");
  __builtin_amdgcn_s_barrier();
  __builtin_amdgcn_sched_barrier(0);
  QUAD(2, 2)
#undef QUAD
}

__global__ __launch_bounds__(512, 2) void gemm_bt(const ushort* __restrict__ A,
                                                  const ushort* __restrict__ Bt,
                                                  const float* __restrict__ bias,
                                                  float* __restrict__ C) {
  extern __shared__ __align__(16) char smem[];
  const int t = threadIdx.x;
  // bijective XCD swizzle: 256 blocks -> 32 contiguous per XCD; consecutive
  // bids share the A-slab (same bm) for L2 locality.
  const int bid = (blockIdx.x & 7) * 32 + (blockIdx.x >> 3);
  const int bm0 = (bid >> 3) << 8;                 // 0..31 -> *256
  const int bn0 = (bid & 7) << 7;                  // 0..7  -> *128
  const int lane = t & 63;
  const int wid  = t >> 6;
  const int wm0 = (wid >> 1) << 6;                 // 0,64,128,192
  const int wn0 = (wid & 1) << 6;                  // 0,64
  const int lr = lane & 15;
  const int lk = lane >> 4;

  // staging source: row = t>>3 (0..63) within 64-row slab, chunk pre-XOR'd
  const int srow = t >> 3;
  const int schunk = ((t & 7) ^ (srow & 7)) << 4;
  const char* gA[4]; const char* gB[2];
  #pragma unroll
  for (int j = 0; j < 4; ++j)
    gA[j] = (const char*)(A + (size_t)(bm0 + j * 64 + srow) * GK) + schunk;
  #pragma unroll
  for (int j = 0; j < 2; ++j)
    gB[j] = (const char*)(Bt + (size_t)(bn0 + j * 64 + srow) * GK) + schunk;
  const int dst = t << 4;

  floatx4 acc[4][4] = {};

  // prologue: stage tile0 -> buf0, tile1 -> buf1; drain tile0 (vmcnt(6)).
  #pragma unroll
  for (int j = 0; j < 4; ++j) gload16(gA[j], smem + j * 8192 + dst);
  #pragma unroll
  for (int j = 0; j < 2; ++j) gload16(gB[j], smem + ABYTES + j * 8192 + dst);
  #pragma unroll
  for (int j = 0; j < 4; ++j) gload16(gA[j] + 128, smem + BUFSZ + j * 8192 + dst);
  #pragma unroll
  for (int j = 0; j < 2; ++j) gload16(gB[j] + 128, smem + BUFSZ + ABYTES + j * 8192 + dst);
  asm volatile("s_waitcnt vmcnt(6)" ::: "memory");
  __builtin_amdgcn_s_barrier();
  __builtin_amdgcn_sched_barrier(0);

  // main loop: tiles 0..125, rotation unrolled by 3
  for (int kt = 0; kt < NT - 2; kt += 3) {
    tile_step<0, 2, true, true>(smem, kt,     gA, gB, dst, wm0, wn0, lr, lk, acc);
    tile_step<1, 0, true, true>(smem, kt + 1, gA, gB, dst, wm0, wn0, lr, lk, acc);
    tile_step<2, 1, true, true>(smem, kt + 2, gA, gB, dst, wm0, wn0, lr, lk, acc);
  }
  // peel tiles 126 (drain-all) and 127
  tile_step<0, 2, false, false>(smem, 126, gA, gB, dst, wm0, wn0, lr, lk, acc);
  tile_step<1, 0, false, false>(smem, 127, gA, gB, dst, wm0, wn0, lr, lk, acc);

  // epilogue: C[row][col] = acc + bias[col]; D layout col=lane&15, row=lk*4+r
  #pragma unroll
  for (int ni = 0; ni < 4; ++ni) {
    const int col = bn0 + wn0 + ni * 16 + lr;
    const float bv = bias[col];
    #pragma unroll
    for (int mi = 0; mi < 4; ++mi) {
      const int row = bm0 + wm0 + mi * 16 + lk * 4;
      #pragma unroll
      for (int r = 0; r < 4; ++r)
        C[(size_t)(row + r) * GN + col] = acc[mi][ni][r] + bv;
    }
  }
}

// ---------------------------------------------------------------------------
extern "C" void kernel_launch(void* const* d_in, const int* in_sizes, int n_in,
                              void* d_out, int out_size, void* d_ws, size_t ws_size,
                              hipStream_t stream) {
  const float* x    = (const float*)d_in[0];
  const float* coef = (const float*)d_in[1];
  float* out = (float*)d_out;

  char* ws = (char*)d_ws;
  ushort* Cf   = (ushort*)ws;                                   // 128 MiB
  ushort* Wt   = (ushort*)(ws + (size_t)BATCH * GK * 2);        //  16 MiB
  float*  bias = (float*)(ws + (size_t)BATCH * GK * 2 + (size_t)GN * GK * 2);

  hipFuncSetAttribute(reinterpret_cast<const void*>(&gemm_bt),
                      hipFuncAttributeMaxDynamicSharedMemorySize, SMEM_BYTES);

  hipMemsetAsync(bias, 0, GN * sizeof(float), stream);
  repack<<<1024, 256, 0, stream>>>(coef, Wt, bias);
  featurize<<<(BATCH * INF / 4) / 256, 256, 0, stream>>>(x, Cf);
  gemm_bt<<<256, 512, SMEM_BYTES, stream>>>(Cf, Wt, bias, out);
}